// Round 2
// baseline (527.530 us; speedup 1.0000x reference)
//
#include <hip/hip_runtime.h>
#include <hip/hip_bf16.h>
#include <math.h>

#define B_ 32
#define T_ 4096
#define D_ 512
#define U_ 512

typedef __bf16 bf16x8 __attribute__((ext_vector_type(8)));
typedef float floatx4 __attribute__((ext_vector_type(4)));
typedef unsigned short ushortx8 __attribute__((ext_vector_type(8)));

// exact RNE float -> bf16 (as uint)
static __device__ __forceinline__ unsigned int f2bf(float f) {
  unsigned int u = __float_as_uint(f);
  return (u + 0x7fffu + ((u >> 16) & 1u)) >> 16;
}

// fast tanh: 1 - 2/(exp2(2x*log2e)+1). v_exp_f32 + v_rcp_f32; exact at +/-inf.
static __device__ __forceinline__ float tanh_fast(float x) {
  float e = exp2f(x * 2.88539008178f);
  return 1.0f - 2.0f * __builtin_amdgcn_rcpf(1.0f + e);
}

// pack 8 fp32 -> 8 bf16 (RNE) as uint4
static __device__ __forceinline__ uint4 pack8(const float4 a, const float4 b) {
  uint4 pk;
  pk.x = f2bf(a.x) | (f2bf(a.y) << 16);
  pk.y = f2bf(a.z) | (f2bf(a.w) << 16);
  pk.z = f2bf(b.x) | (f2bf(b.y) << 16);
  pk.w = f2bf(b.z) | (f2bf(b.w) << 16);
  return pk;
}

// ---------------------------------------------------------------------------
// P0: pack W2 (fp32 [k][u]) into MFMA-fragment-ordered bf16:
//   W2B[((ub*16 + kb)*64 + lane)*8 + j]
//     = bf16(W2[(kb*32 + (lane>>4)*8 + j)][ub*16 + (lane&15)])
// ---------------------------------------------------------------------------
__global__ __launch_bounds__(256) void prep_w2b(
    const float* __restrict__ W2, unsigned short* __restrict__ W2B) {
  const int s = blockIdx.x * 256 + threadIdx.x;  // slot id
  const int lane = s & 63;
  const int frag = s >> 6;       // 0..511
  const int ub = frag >> 4;      // u-block of 16
  const int kb = frag & 15;      // k-block of 32
  const int lr = lane & 15;
  const int kc = lane >> 4;
  const int u = ub * 16 + lr;
  const int k0 = kb * 32 + kc * 8;
  ushortx8 pk;
#pragma unroll
  for (int j = 0; j < 8; ++j)
    pk[j] = (unsigned short)f2bf(W2[(size_t)(k0 + j) * U_ + u]);
  *(ushortx8*)&W2B[(size_t)s * 8] = pk;
}

// ---------------------------------------------------------------------------
// K1: q_proj[b][u] = query[b]@W1[:,u] + b1[u] + b2[u]
// grid (B, 8) = 256 blocks; block = 64 u-cols x 4 k-quarters.
// ---------------------------------------------------------------------------
__global__ __launch_bounds__(256) void qproj_kernel(
    const float* __restrict__ query, const float* __restrict__ W1,
    const float* __restrict__ b1, const float* __restrict__ b2,
    float* __restrict__ qp) {
  const int b = blockIdx.x;
  const int ug = blockIdx.y;        // u-group of 64
  const int tid = threadIdx.x;
  const int uq = tid & 63;
  const int kq = tid >> 6;          // k-quarter 0..3
  __shared__ float qs[D_];
  __shared__ float red[4][64];
  qs[tid] = query[b * D_ + tid];
  qs[tid + 256] = query[b * D_ + tid + 256];
  __syncthreads();
  const int u = ug * 64 + uq;
  float a = 0.f;
#pragma unroll 8
  for (int k = kq * 128; k < kq * 128 + 128; ++k)
    a += qs[k] * W1[(size_t)k * U_ + u];
  red[kq][uq] = a;
  __syncthreads();
  if (tid < 64) {
    const int uu = ug * 64 + tid;
    qp[b * U_ + uu] =
        red[0][tid] + red[1][tid] + red[2][tid] + red[3][tid] + b1[uu] + b2[uu];
  }
}

// ---------------------------------------------------------------------------
// K2: streaming scores. 256 blocks (one per CU), 512 threads = 8 waves
// (u-split: wave w owns u in [w*64, w*64+64)). Each block owns 8 consecutive
// 64-row t-tiles (1 MB of contiguous values). Double-buffered A tile in
// STATIC LDS (2 x 64 KB, XOR swizzle k8^(r&7), + 4 KB reduce scratch =
// 132 KB of the 160 KB/CU; 1 block/CU, 8 waves). Staged loads for tile n+1
// are ISSUED before the K-loop of tile n and written after it (T14), so HBM
// draw is continuous across the whole kernel. Epilogue computes
// w = exp(score) directly (|s| <= ||V||_1 ~ 8, fp32-safe without max
// subtraction); the separate softmax kernel is eliminated.
// One __syncthreads per tile; redp parity gives readers a full barrier of
// separation from the next writer.
// ---------------------------------------------------------------------------
__global__ __launch_bounds__(512, 2) void scores_mfma(
    const float* __restrict__ values, const unsigned short* __restrict__ W2B,
    const float* __restrict__ qp, const float* __restrict__ V,
    float* __restrict__ wexp) {
  // 2 x 64 rows x 512 k bf16 = 128 KB (static; gfx950 LDS is 160 KB/CU)
  __shared__ __align__(16) unsigned short As[2 * 64 * 512];
  __shared__ float redp[2 * 512];  // [parity][wave][row]

  const int b = blockIdx.y;
  const int tg = blockIdx.x;          // t-group: 512 rows
  const int tid = threadIdx.x;
  const int w = tid >> 6;             // wave 0..7
  const int lane = tid & 63;
  const int lr = lane & 15;           // fragment row within 16
  const int kc = lane >> 4;           // k-chunk 0..3 (8 bf16 each)
  const int w4 = w * 4;

  const float* vbase = values + ((size_t)b * T_ + (size_t)tg * 512) * D_;
  const ushortx8* W2Bv = (const ushortx8*)W2B;

  // per-wave u-slice constants: u = w*64 + j*16 + lr
  float qv[4], vv[4];
  const float* qpb = qp + b * U_;
#pragma unroll
  for (int j = 0; j < 4; ++j) {
    const int u = w * 64 + j * 16 + lr;
    qv[j] = qpb[u];
    vv[j] = V[u];
  }

  // ---- prologue: stage tile 0 into buffer 0 ----
  {
#pragma unroll
    for (int p = 0; p < 8; ++p) {
      const int r = p * 8 + w;                 // row (wave-uniform), r&7 == w
      const float* rp = vbase + (size_t)r * D_ + lane * 8;
      const float4 f0 = *(const float4*)rp;
      const float4 f1 = *(const float4*)(rp + 4);
      *(uint4*)&As[r * 512 + (lane ^ w) * 8] = pack8(f0, f1);
    }
  }
  __syncthreads();

  for (int n = 0; n < 8; ++n) {
    const int cur = n & 1;
    const unsigned short* Asc = As + cur * 32768;

    // 1. issue staged loads for tile n+1 (in flight across the K-loop)
    float4 sv[16];
    if (n + 1 < 8) {
      const float* tb = vbase + (size_t)(n + 1) * 64 * D_;
#pragma unroll
      for (int p = 0; p < 8; ++p) {
        const float* rp = tb + (size_t)(p * 8 + w) * D_ + lane * 8;
        sv[2 * p] = *(const float4*)rp;
        sv[2 * p + 1] = *(const float4*)(rp + 4);
      }
    }

    // 2. K loop: no barriers; 4 B-frag L2 loads + 4 ds_read_b128 + 16 MFMA
    floatx4 acc[4][4];
#pragma unroll
    for (int i = 0; i < 4; ++i)
#pragma unroll
      for (int j = 0; j < 4; ++j) acc[i][j] = (floatx4)0.f;

#pragma unroll 4
    for (int ks = 0; ks < 16; ++ks) {
      bf16x8 bfr[4];
#pragma unroll
      for (int j = 0; j < 4; ++j)
        bfr[j] = __builtin_bit_cast(
            bf16x8, W2Bv[((w4 + j) * 16 + ks) * 64 + lane]);
      const int c = (ks * 4 + kc) ^ (lr & 7);   // ri&7 == lr&7 for all i
      bf16x8 af[4];
#pragma unroll
      for (int i = 0; i < 4; ++i) {
        const int ri = i * 16 + lr;
        af[i] =
            __builtin_bit_cast(bf16x8, *(const ushortx8*)&Asc[ri * 512 + c * 8]);
      }
#pragma unroll
      for (int i = 0; i < 4; ++i)
#pragma unroll
        for (int j = 0; j < 4; ++j)
          acc[i][j] = __builtin_amdgcn_mfma_f32_16x16x32_bf16(
              af[i], bfr[j], acc[i][j], 0, 0, 0);
    }

    // 3. epilogue partials: C/D layout u = w*64+j*16+lr, t = i*16+kc*4+r
#pragma unroll
    for (int i = 0; i < 4; ++i) {
#pragma unroll
      for (int r = 0; r < 4; ++r) {
        float s = 0.f;
#pragma unroll
        for (int j = 0; j < 4; ++j) s += tanh_fast(acc[i][j][r] + qv[j]) * vv[j];
        s += __shfl_xor(s, 1);
        s += __shfl_xor(s, 2);
        s += __shfl_xor(s, 4);
        s += __shfl_xor(s, 8);
        if (lr == 0) redp[cur * 512 + w * 64 + i * 16 + kc * 4 + r] = s;
      }
    }

    // 4. pack + write next tile into the other buffer (waits on sv here)
    if (n + 1 < 8) {
      unsigned short* Asn = As + (cur ^ 1) * 32768;
      const int c = lane ^ w;
#pragma unroll
      for (int p = 0; p < 8; ++p) {
        const int r = p * 8 + w;
        *(uint4*)&Asn[r * 512 + c * 8] = pack8(sv[2 * p], sv[2 * p + 1]);
      }
    }

    __syncthreads();

    // 5. cross-wave reduce (8 partials per row) + exp + global write
    {
      const int row = tid >> 3;       // 0..63
      const int p = tid & 7;
      float s = redp[cur * 512 + p * 64 + row];
      s += __shfl_xor(s, 1);
      s += __shfl_xor(s, 2);
      s += __shfl_xor(s, 4);
      if (p == 0)
        wexp[(size_t)b * T_ + tg * 512 + n * 64 + row] = expf(s);
    }
  }
}

// ---------------------------------------------------------------------------
// K4: context[b][d] = sum_t w[b][t]*values[b][t][d] / sum_t w[b][t]
// den recomputed per block (16 KB scan, trivial vs the 256 KB values read).
// grid (B, 32): 128 t-rows per block; 256 thr = 2 rows x 128 float4 lanes.
// ---------------------------------------------------------------------------
__global__ __launch_bounds__(256) void context_kernel(
    const float* __restrict__ values, const float* __restrict__ wexp,
    float* __restrict__ out) {
  const int b = blockIdx.x;
  const int t0 = blockIdx.y * 128;
  const int tid = threadIdx.x;
  const int tx = tid & 127;
  const int ty = tid >> 7;
  __shared__ float as[128];
  __shared__ float4 redv[128];
  __shared__ float dred[4];

  const float* wb = wexp + (size_t)b * T_;
  // denominator: full-T scan (coalesced), wave reduce, 4 wave partials
  float lsum = 0.f;
#pragma unroll
  for (int i = 0; i < 16; ++i) lsum += wb[i * 256 + tid];
#pragma unroll
  for (int off = 1; off < 64; off <<= 1) lsum += __shfl_xor(lsum, off);
  if ((tid & 63) == 0) dred[tid >> 6] = lsum;
  __syncthreads();
  const float scale = 1.0f / (dred[0] + dred[1] + dred[2] + dred[3]);
  if (tid < 128) as[tid] = wb[t0 + tid] * scale;
  __syncthreads();

  const float* vb = values + ((size_t)b * T_ + t0) * D_;
  float ax = 0.f, ay = 0.f, az = 0.f, aw = 0.f;
#pragma unroll 8
  for (int t = ty; t < 128; t += 2) {
    const float a = as[t];
    const float4 v = *(const float4*)&vb[(size_t)t * D_ + tx * 4];
    ax += a * v.x;
    ay += a * v.y;
    az += a * v.z;
    aw += a * v.w;
  }
  if (ty == 1) redv[tx] = make_float4(ax, ay, az, aw);
  __syncthreads();
  if (ty == 0) {
    const float4 o = redv[tx];
    const int d = tx * 4;
    atomicAdd(&out[b * D_ + d],     ax + o.x);
    atomicAdd(&out[b * D_ + d + 1], ay + o.y);
    atomicAdd(&out[b * D_ + d + 2], az + o.z);
    atomicAdd(&out[b * D_ + d + 3], aw + o.w);
  }
}

// ---------------------------------------------------------------------------
extern "C" void kernel_launch(void* const* d_in, const int* in_sizes, int n_in,
                              void* d_out, int out_size, void* d_ws,
                              size_t ws_size, hipStream_t stream) {
  const float* query = (const float*)d_in[0];
  const float* values = (const float*)d_in[1];
  const float* W1 = (const float*)d_in[2];
  const float* b1 = (const float*)d_in[3];
  const float* W2 = (const float*)d_in[4];
  const float* b2 = (const float*)d_in[5];
  const float* V = (const float*)d_in[6];
  // d_in[7] = bv : dropped (softmax shift-invariant; cancels in context)

  // ws layout: qp (64 KB) | wexp (512 KB) | W2B bf16 packed (512 KB)
  float* qp = (float*)d_ws;
  float* wexp = qp + (size_t)B_ * U_;
  unsigned short* W2B = (unsigned short*)(wexp + (size_t)B_ * T_);
  float* out = (float*)d_out;

  (void)hipMemsetAsync(d_out, 0, (size_t)B_ * D_ * sizeof(float), stream);

  prep_w2b<<<128, 256, 0, stream>>>(W2, W2B);
  qproj_kernel<<<dim3(B_, 8), 256, 0, stream>>>(query, W1, b1, b2, qp);
  scores_mfma<<<dim3(8, B_), 512, 0, stream>>>(values, W2B, qp, V, wexp);
  context_kernel<<<dim3(B_, 32), 256, 0, stream>>>(values, wexp, out);
}